// Round 4
// baseline (631.781 us; speedup 1.0000x reference)
//
#include <hip/hip_runtime.h>

#define N_NODES 100000
#define DIM 64
#define N_EDGES 1250000
#define EPS 1e-12f

#define PART 128                          // nodes per partition
#define NP ((N_NODES + PART - 1) / PART)  // 782 partitions
#define SLOT 2048                         // edge slots/partition (mean 1600, +11 sigma)
#define CSTRIDE 16                        // pcursor padding: 1 cursor per 64B line
#define CH 4096                           // edges per bucket block
#define NCH ((N_EDGES + CH - 1) / CH)     // 306 bucket blocks
#define BT 512                            // threads (8 waves -> 4 blocks/CU)
#define EPT (CH / BT)                     // 8 edges per thread
#define NCV ((N_NODES * DIM / 8 + BT - 1) / BT)   // 1563 convert blocks

#define ASTRIDE 68   // lacc row stride in floats: (4d+8sub+k)%32 uniform 2/bank

typedef unsigned short ushort8 __attribute__((ext_vector_type(8)));

__device__ inline unsigned short f2bf(float f) {   // fp32 -> bf16 RNE
    unsigned int u = __float_as_uint(f);
    return (unsigned short)((u + 0x7FFFu + ((u >> 16) & 1u)) >> 16);
}
__device__ inline float bf2f(unsigned short h) {
    return __uint_as_float(((unsigned int)h) << 16);
}

// ---- Pass 1 (fused): blocks [0,NCH) bucket edges by dst partition (LDS
// counting sort, fully-parallel coalesced dump); blocks [NCH,..) stream-
// convert x fp32 -> bf16. Independent workloads overlap on the device.
// (Round-14 note: cooperative grid.sync fusion FAILS under graph capture —
// this 3-dispatch structure is the working floor.)
__global__ __launch_bounds__(BT)
void convert_bucket_kernel(const float4* __restrict__ x4,
                           ushort8* __restrict__ xh8,
                           const int* __restrict__ src,
                           const int* __restrict__ dst,
                           int* __restrict__ pcursor,
                           int* __restrict__ ebuf) {
    __shared__ int hist[NP];               // per-bin counts
    __shared__ int lstart[NP];             // exclusive prefix (LDS run start)
    __shared__ int cur[NP];                // placement cursors
    __shared__ int gb[NP];                 // global slab base per bin
    __shared__ int sorted[CH];             // packed edges grouped by bin (16 KB)
    __shared__ unsigned short pb[CH];      // bin id per sorted slot (8 KB)
    __shared__ int wsum[BT / 64];

    int t = threadIdx.x;

    if (blockIdx.x >= NCH) {               // ---- convert branch ----
        int i = (blockIdx.x - NCH) * BT + t;
        if (i < N_NODES * DIM / 8) {
            float4 a = x4[2 * i];
            float4 b = x4[2 * i + 1];
            ushort8 o;
            o[0] = f2bf(a.x); o[1] = f2bf(a.y); o[2] = f2bf(a.z); o[3] = f2bf(a.w);
            o[4] = f2bf(b.x); o[5] = f2bf(b.y); o[6] = f2bf(b.z); o[7] = f2bf(b.w);
            xh8[i] = o;
        }
        return;
    }

    // ---- bucket branch ----
    int e0 = blockIdx.x * CH;
    for (int p = t; p < NP; p += BT) hist[p] = 0;
    __syncthreads();

    int d[EPT];
    #pragma unroll
    for (int i = 0; i < EPT; ++i) {
        int e = e0 + i * BT + t;
        d[i] = (e < N_EDGES) ? dst[e] : -1;
        if (d[i] >= 0) atomicAdd(&hist[d[i] >> 7], 1);   // LDS, non-returning
    }
    __syncthreads();

    // global slab base per bin (block-granular returning atomics: 306x782)
    for (int p = t; p < NP; p += BT) {
        int c = hist[p];
        gb[p] = c ? atomicAdd(&pcursor[p * CSTRIDE], c) : 0;
    }

    // shfl-based exclusive scan over 782 bins, 2 bins/thread, 2 barriers
    int lane = t & 63, w = t >> 6;
    int b0 = 2 * t, b1 = 2 * t + 1;
    int c0 = (b0 < NP) ? hist[b0] : 0;
    int c1 = (b1 < NP) ? hist[b1] : 0;
    int ms = c0 + c1;
    int v = ms;
    #pragma unroll
    for (int off = 1; off < 64; off <<= 1) {
        int u = __shfl_up(v, off, 64);
        if (lane >= off) v += u;
    }
    if (lane == 63) wsum[w] = v;
    __syncthreads();
    if (t == 0) {
        int run = 0;
        #pragma unroll
        for (int i = 0; i < BT / 64; ++i) { int c = wsum[i]; wsum[i] = run; run += c; }
    }
    __syncthreads();
    int excl = wsum[w] + v - ms;
    if (b0 < NP) { lstart[b0] = excl;      cur[b0] = excl; }
    if (b1 < NP) { lstart[b1] = excl + c0; cur[b1] = excl + c0; }
    __syncthreads();

    // place into LDS (native int LDS atomics), record bin per slot
    #pragma unroll
    for (int i = 0; i < EPT; ++i) {
        if (d[i] >= 0) {
            int e = e0 + i * BT + t;
            int p = d[i] >> 7;
            int pos = atomicAdd(&cur[p], 1);
            sorted[pos] = (src[e] << 7) | (d[i] & 127);
            pb[pos] = (unsigned short)p;
        }
    }
    __syncthreads();

    // fully-parallel dump: every thread stores one element; consecutive
    // slots within a bin -> consecutive global addresses (runs ~5)
    int vcnt = min(CH, N_EDGES - e0);
    for (int i = t; i < vcnt; i += BT) {
        int pk = sorted[i];
        int p = pb[i];
        ebuf[p * SLOT + gb[p] + (i - lstart[p])] = pk;
    }
}

// ---- Pass 2 (round-4 restructure): edge-parallel gather + LDS f32
// accumulation. One 8-lane group per edge per trip: lane sub loads 16B of
// the bf16 src row, converts, ds_add_f32 into lacc[dst][dim]. No CSR
// build, no degree divergence, and consecutive trips are fully
// independent (only consumer is a non-returning LDS atomic) -> load
// latency pipelines. Stride 68: wave's 64 atomic addrs = 2/bank (free).
__global__ __launch_bounds__(BT, 8)
void aggregate_kernel(const ushort8* __restrict__ xh8,
                      const int* __restrict__ pcursor,
                      const int* __restrict__ ebuf,
                      float* __restrict__ out) {
    __shared__ float lacc[PART * ASTRIDE];   // 128 x 68 f32 = 34.8 KB
    int p = blockIdx.x;
    int t = threadIdx.x;
    int g = t >> 3, sub = t & 7;

    for (int i = t; i < PART * ASTRIDE; i += BT) lacc[i] = 0.f;
    __syncthreads();

    int cnt = pcursor[p * CSTRIDE];
    const int* __restrict__ eb = ebuf + p * SLOT;

    // 64 groups sweep the edge list; all 8 lanes of a group share edge i
    for (int i = g; i < cnt; i += BT / 8) {
        int pk = eb[i];                       // broadcast load (same addr)
        int s = pk >> 7;
        int d = pk & 127;
        ushort8 vv = xh8[(size_t)s * 8 + sub];
        float* a = &lacc[d * ASTRIDE + sub * 8];
        #pragma unroll
        for (int k = 0; k < 8; ++k) atomicAdd(&a[k], bf2f(vv[k]));
    }
    __syncthreads();

    // finalize: 8-lane group per node, lane sub owns dims [8*sub, 8*sub+8)
    #pragma unroll
    for (int q = 0; q < 2; ++q) {
        int nl = q * 64 + g;
        int gnode = p * PART + nl;
        const float* a = &lacc[nl * ASTRIDE + sub * 8];
        float v0 = a[0], v1 = a[1], v2 = a[2], v3 = a[3];
        float v4 = a[4], v5 = a[5], v6 = a[6], v7 = a[7];

        float ss = v0*v0 + v1*v1 + v2*v2 + v3*v3 + v4*v4 + v5*v5 + v6*v6 + v7*v7;
        ss += __shfl_xor(ss, 1, 64);
        ss += __shfl_xor(ss, 2, 64);
        ss += __shfl_xor(ss, 4, 64);

        float scale = 2.0f / fmaxf(sqrtf(ss), EPS);
        if (gnode < N_NODES) {
            float4 o0, o1;
            o0.x = fmaxf(v0 * scale, 0.f); o0.y = fmaxf(v1 * scale, 0.f);
            o0.z = fmaxf(v2 * scale, 0.f); o0.w = fmaxf(v3 * scale, 0.f);
            o1.x = fmaxf(v4 * scale, 0.f); o1.y = fmaxf(v5 * scale, 0.f);
            o1.z = fmaxf(v6 * scale, 0.f); o1.w = fmaxf(v7 * scale, 0.f);
            ((float4*)out)[(size_t)gnode * 16 + 2 * sub]     = o0;
            ((float4*)out)[(size_t)gnode * 16 + 2 * sub + 1] = o1;
        }
    }
}

extern "C" void kernel_launch(void* const* d_in, const int* in_sizes, int n_in,
                              void* d_out, int out_size, void* d_ws, size_t ws_size,
                              hipStream_t stream) {
    const float* x  = (const float*)d_in[0];
    const int*   ei = (const int*)d_in[1];
    float* out = (float*)d_out;

    const int* src = ei;
    const int* dst = ei + N_EDGES;

    // ws: xh[12.8 MB bf16] | pcursor[782*16 ints, line-padded] | ebuf[6.4 MB]
    ushort8* xh  = (ushort8*)d_ws;
    int* pcursor = (int*)((char*)d_ws + (size_t)N_NODES * DIM * 2);
    int* ebuf    = pcursor + NP * CSTRIDE;

    hipMemsetAsync(pcursor, 0, NP * CSTRIDE * sizeof(int), stream);

    convert_bucket_kernel<<<NCH + NCV, BT, 0, stream>>>(
        (const float4*)x, xh, src, dst, pcursor, ebuf);

    aggregate_kernel<<<NP, BT, 0, stream>>>(xh, pcursor, ebuf, out);
}

// Round 5
// 134.667 us; speedup vs baseline: 4.6914x; 4.6914x over previous
//
#include <hip/hip_runtime.h>

#define N_NODES 100000
#define DIM 64
#define N_EDGES 1250000
#define EPS 1e-12f

#define PART 128                          // nodes per partition
#define NP ((N_NODES + PART - 1) / PART)  // 782 partitions
#define SLOT 2048                         // edge slots/partition (mean 1600, +11 sigma)
#define CSTRIDE 16                        // pcursor padding: 1 cursor per 64B line
#define CH 4096                           // edges per bucket block
#define NCH ((N_EDGES + CH - 1) / CH)     // 306 bucket blocks
#define BT 512                            // threads (8 waves -> 4 blocks/CU)
#define EPT (CH / BT)                     // 8 edges per thread
#define NCV ((N_NODES * DIM / 8 + BT - 1) / BT)   // 1563 convert blocks

typedef unsigned short ushort8 __attribute__((ext_vector_type(8)));

__device__ inline unsigned short f2bf(float f) {   // fp32 -> bf16 RNE
    unsigned int u = __float_as_uint(f);
    return (unsigned short)((u + 0x7FFFu + ((u >> 16) & 1u)) >> 16);
}
__device__ inline float bf2f(unsigned short h) {
    return __uint_as_float(((unsigned int)h) << 16);
}

// ---- Pass 1 (fused): blocks [0,NCH) bucket edges by dst partition (LDS
// counting sort, fully-parallel coalesced dump); blocks [NCH,..) stream-
// convert x fp32 -> bf16. Independent workloads overlap on the device.
// (Round-14 note: cooperative grid.sync fusion FAILS under graph capture —
// this 3-dispatch structure is the working floor.)
__global__ __launch_bounds__(BT)
void convert_bucket_kernel(const float4* __restrict__ x4,
                           ushort8* __restrict__ xh8,
                           const int* __restrict__ src,
                           const int* __restrict__ dst,
                           int* __restrict__ pcursor,
                           int* __restrict__ ebuf) {
    __shared__ int hist[NP];               // per-bin counts
    __shared__ int lstart[NP];             // exclusive prefix (LDS run start)
    __shared__ int cur[NP];                // placement cursors
    __shared__ int gb[NP];                 // global slab base per bin
    __shared__ int sorted[CH];             // packed edges grouped by bin (16 KB)
    __shared__ unsigned short pb[CH];      // bin id per sorted slot (8 KB)
    __shared__ int wsum[BT / 64];

    int t = threadIdx.x;

    if (blockIdx.x >= NCH) {               // ---- convert branch ----
        int i = (blockIdx.x - NCH) * BT + t;
        if (i < N_NODES * DIM / 8) {
            float4 a = x4[2 * i];
            float4 b = x4[2 * i + 1];
            ushort8 o;
            o[0] = f2bf(a.x); o[1] = f2bf(a.y); o[2] = f2bf(a.z); o[3] = f2bf(a.w);
            o[4] = f2bf(b.x); o[5] = f2bf(b.y); o[6] = f2bf(b.z); o[7] = f2bf(b.w);
            xh8[i] = o;
        }
        return;
    }

    // ---- bucket branch ----
    int e0 = blockIdx.x * CH;
    for (int p = t; p < NP; p += BT) hist[p] = 0;
    __syncthreads();

    int d[EPT];
    #pragma unroll
    for (int i = 0; i < EPT; ++i) {
        int e = e0 + i * BT + t;
        d[i] = (e < N_EDGES) ? dst[e] : -1;
        if (d[i] >= 0) atomicAdd(&hist[d[i] >> 7], 1);   // LDS, non-returning
    }
    __syncthreads();

    // global slab base per bin (block-granular returning atomics: 306x782)
    for (int p = t; p < NP; p += BT) {
        int c = hist[p];
        gb[p] = c ? atomicAdd(&pcursor[p * CSTRIDE], c) : 0;
    }

    // shfl-based exclusive scan over 782 bins, 2 bins/thread, 2 barriers
    int lane = t & 63, w = t >> 6;
    int b0 = 2 * t, b1 = 2 * t + 1;
    int c0 = (b0 < NP) ? hist[b0] : 0;
    int c1 = (b1 < NP) ? hist[b1] : 0;
    int ms = c0 + c1;
    int v = ms;
    #pragma unroll
    for (int off = 1; off < 64; off <<= 1) {
        int u = __shfl_up(v, off, 64);
        if (lane >= off) v += u;
    }
    if (lane == 63) wsum[w] = v;
    __syncthreads();
    if (t == 0) {
        int run = 0;
        #pragma unroll
        for (int i = 0; i < BT / 64; ++i) { int c = wsum[i]; wsum[i] = run; run += c; }
    }
    __syncthreads();
    int excl = wsum[w] + v - ms;
    if (b0 < NP) { lstart[b0] = excl;      cur[b0] = excl; }
    if (b1 < NP) { lstart[b1] = excl + c0; cur[b1] = excl + c0; }
    __syncthreads();

    // place into LDS (native int LDS atomics), record bin per slot
    #pragma unroll
    for (int i = 0; i < EPT; ++i) {
        if (d[i] >= 0) {
            int e = e0 + i * BT + t;
            int p = d[i] >> 7;
            int pos = atomicAdd(&cur[p], 1);
            sorted[pos] = (src[e] << 7) | (d[i] & 127);
            pb[pos] = (unsigned short)p;
        }
    }
    __syncthreads();

    // fully-parallel dump: every thread stores one element; consecutive
    // slots within a bin -> consecutive global addresses (runs ~5)
    int vcnt = min(CH, N_EDGES - e0);
    for (int i = t; i < vcnt; i += BT) {
        int pk = sorted[i];
        int p = pb[i];
        ebuf[p * SLOT + gb[p] + (i - lstart[p])] = pk;
    }
}

// ---- Pass 2: one 512-thread block per partition. Build 128-node CSR in
// LDS (shfl scan, 2 barriers), then node-per-lane-group gather.
// Round-5 change (the ONLY change vs the 132.4 us round-1 kernel): the
// two 64-node halves (q=0,1) are processed in ONE interleaved trip loop
// with acc[2][8]. Doubles loads-in-flight 8->16 and replaces
// max(t0)+max(t1) divergent trips with max(t0,t1). Per-node summation
// order is bit-identical to round-1. launch_bounds(512,6): VGPR cap ~85
// so the second accumulator doesn't spill (782 blocks -> ~3/CU anyway).
__global__ __launch_bounds__(BT, 6)
void aggregate_kernel(const ushort8* __restrict__ xh8,
                      const int* __restrict__ pcursor,
                      const int* __restrict__ ebuf,
                      float* __restrict__ out) {
    __shared__ int lraw[SLOT];    // raw packed edges (8 KB)
    __shared__ int lcsr[SLOT];    // src ids, CSR-ordered (8 KB)
    __shared__ int lhist[PART];   // counts -> inclusive prefix
    __shared__ int lcur[PART];    // exclusive prefix -> placement cursor
    __shared__ int bridge;
    int p = blockIdx.x;
    int t = threadIdx.x;
    int lane = t & 63, w = t >> 6;
    int n = lane >> 3, sub = lane & 7;

    if (t < PART) lhist[t] = 0;
    __syncthreads();

    int cnt = pcursor[p * CSTRIDE];
    const int* __restrict__ eb = ebuf + p * SLOT;
    for (int i = t; i < cnt; i += BT) {
        int pk = eb[i];
        lraw[i] = pk;
        atomicAdd(&lhist[pk & 127], 1);
    }
    __syncthreads();

    // shfl scan over 128 bins (threads 0..127 = waves 0,1), 2 barriers
    int myc = 0, vincl = 0;
    if (t < PART) {
        myc = lhist[t];
        vincl = myc;
        #pragma unroll
        for (int off = 1; off < 64; off <<= 1) {
            int u = __shfl_up(vincl, off, 64);
            if (lane >= off) vincl += u;
        }
        if (t == 63) bridge = vincl;
    }
    __syncthreads();
    if (t < PART) {
        int add = (t >= 64) ? bridge : 0;
        lhist[t] = vincl + add;          // inclusive prefix
        lcur[t]  = vincl + add - myc;    // exclusive prefix
    }
    __syncthreads();

    for (int i = t; i < cnt; i += BT) {
        int pk = lraw[i];
        int pos = atomicAdd(&lcur[pk & 127], 1);
        lcsr[pos] = pk >> 7;
    }
    __syncthreads();

    // interleaved dual-node gather: 8 waves x 8 groups, each group owns
    // nodes nl0 (=w*8+n) and nl1 (=64+w*8+n) simultaneously
    int nl0 = w * 8 + n;
    int nl1 = 64 + w * 8 + n;
    int beg0 = nl0 ? lhist[nl0 - 1] : 0;
    int end0 = lhist[nl0];
    int beg1 = lhist[nl1 - 1];
    int end1 = lhist[nl1];
    int dn0 = end0 - beg0;
    int dn1 = end1 - beg1;
    int tmax = max(dn0, dn1);

    float acc[2][8] = {{0.f,0.f,0.f,0.f,0.f,0.f,0.f,0.f},
                       {0.f,0.f,0.f,0.f,0.f,0.f,0.f,0.f}};
    for (int e = 0; e < tmax; e += 8) {
        #pragma unroll
        for (int i = 0; i < 8; ++i) {
            if (e + i < dn0) {
                int s = lcsr[beg0 + e + i];
                ushort8 vv = xh8[(size_t)s * 8 + sub];
                #pragma unroll
                for (int k = 0; k < 8; ++k) acc[0][k] += bf2f(vv[k]);
            }
            if (e + i < dn1) {
                int s = lcsr[beg1 + e + i];
                ushort8 vv = xh8[(size_t)s * 8 + sub];
                #pragma unroll
                for (int k = 0; k < 8; ++k) acc[1][k] += bf2f(vv[k]);
            }
        }
    }

    #pragma unroll
    for (int q = 0; q < 2; ++q) {
        int nl = q * 64 + w * 8 + n;
        int gnode = p * PART + nl;
        float ss = 0.f;
        #pragma unroll
        for (int k = 0; k < 8; ++k) ss += acc[q][k] * acc[q][k];
        ss += __shfl_xor(ss, 1, 64);
        ss += __shfl_xor(ss, 2, 64);
        ss += __shfl_xor(ss, 4, 64);

        float scale = 2.0f / fmaxf(sqrtf(ss), EPS);
        if (gnode < N_NODES) {
            float4 o0, o1;
            o0.x = fmaxf(acc[q][0] * scale, 0.f); o0.y = fmaxf(acc[q][1] * scale, 0.f);
            o0.z = fmaxf(acc[q][2] * scale, 0.f); o0.w = fmaxf(acc[q][3] * scale, 0.f);
            o1.x = fmaxf(acc[q][4] * scale, 0.f); o1.y = fmaxf(acc[q][5] * scale, 0.f);
            o1.z = fmaxf(acc[q][6] * scale, 0.f); o1.w = fmaxf(acc[q][7] * scale, 0.f);
            ((float4*)out)[(size_t)gnode * 16 + 2 * sub]     = o0;
            ((float4*)out)[(size_t)gnode * 16 + 2 * sub + 1] = o1;
        }
    }
}

extern "C" void kernel_launch(void* const* d_in, const int* in_sizes, int n_in,
                              void* d_out, int out_size, void* d_ws, size_t ws_size,
                              hipStream_t stream) {
    const float* x  = (const float*)d_in[0];
    const int*   ei = (const int*)d_in[1];
    float* out = (float*)d_out;

    const int* src = ei;
    const int* dst = ei + N_EDGES;

    // ws: xh[12.8 MB bf16] | pcursor[782*16 ints, line-padded] | ebuf[6.4 MB]
    ushort8* xh  = (ushort8*)d_ws;
    int* pcursor = (int*)((char*)d_ws + (size_t)N_NODES * DIM * 2);
    int* ebuf    = pcursor + NP * CSTRIDE;

    hipMemsetAsync(pcursor, 0, NP * CSTRIDE * sizeof(int), stream);

    convert_bucket_kernel<<<NCH + NCV, BT, 0, stream>>>(
        (const float4*)x, xh, src, dst, pcursor, ebuf);

    aggregate_kernel<<<NP, BT, 0, stream>>>(xh, pcursor, ebuf, out);
}